// Round 13
// baseline (30.417 us; speedup 1.0000x reference)
//
#include <hip/hip_runtime.h>
#include <cstdint>
#include <cfloat>
#include <cstddef>

#define BB 8
#define VV 2048
#define SS 4
#define FF 64
#define KK 8

// Largest f32 that stays FINITE when rounded to bf16 (FLT_MAX -> bf16 = +inf).
#define BF16_SAFE_MAX 3.3e38f

typedef unsigned long long u64;
typedef unsigned int u32;

// ---- f64-packed keys: value order == (dist_bits, index) lexicographic ----
// bits = (1<<62) | (dist_bits << 20) | w -> normal positive double, never NaN.
// dist_bits may be FLT_MAX (masked, == ref MAX_DIST) or +inf (double-masked);
// both sort after all real keys and among themselves by index == ref's stable
// tie-break. fmin/fmax (v_min_f64/v_max_f64) = 2-instruction CE.
#define KEY_BIAS (1ULL << 62)

static __forceinline__ __device__ double mk_key(float d, u32 w) {
    return __longlong_as_double(
        (long long)(KEY_BIAS | ((u64)__float_as_uint(d) << 20) | (u64)w));
}
static __forceinline__ __device__ u32 key_dist(double k) {
    return (u32)(((u64)__double_as_longlong(k)) >> 20);
}
static __forceinline__ __device__ u32 key_idx(double k) {
    return (u32)((u64)__double_as_longlong(k) & (u64)(VV - 1));
}
static __forceinline__ __device__ double shfl_xor_f64(double x, int m) {
    const u64 b = (u64)__double_as_longlong(x);
    int lo = __shfl_xor((int)(u32)b, m, 64);
    int hi = __shfl_xor((int)(u32)(b >> 32), m, 64);
    return __longlong_as_double((long long)(((u64)(u32)hi << 32) | (u32)lo));
}
static __forceinline__ __device__ void nt_store_f2(float* p, float2 v) {
    union { float2 f; u64 u; } c; c.f = v;
    __builtin_nontemporal_store(c.u, (u64*)p);
}

#define CED(A, x, y) { double lo_ = fmin(A[x], A[y]);                          \
                       double hi_ = fmax(A[x], A[y]);                          \
                       A[x] = lo_; A[y] = hi_; }

// Batcher odd-even mergesort, n=8, 19 comparators, on A[O..O+7]
#define SORT8D(K, O)                                                           \
    CED(K,O+0,O+1) CED(K,O+2,O+3) CED(K,O+4,O+5) CED(K,O+6,O+7)                \
    CED(K,O+0,O+2) CED(K,O+1,O+3) CED(K,O+4,O+6) CED(K,O+5,O+7)                \
    CED(K,O+1,O+2) CED(K,O+5,O+6)                                              \
    CED(K,O+0,O+4) CED(K,O+1,O+5) CED(K,O+2,O+6) CED(K,O+3,O+7)                \
    CED(K,O+2,O+4) CED(K,O+3,O+5)                                              \
    CED(K,O+1,O+2) CED(K,O+3,O+4) CED(K,O+5,O+6)

// bitonic clean of t[0..7] (strides 4,2,1)
#define CLEAN8D(t)                                                             \
    CED(t,0,4) CED(t,1,5) CED(t,2,6) CED(t,3,7)                                \
    CED(t,0,2) CED(t,1,3) CED(t,4,6) CED(t,5,7)                                \
    CED(t,0,1) CED(t,2,3) CED(t,4,5) CED(t,6,7)

// merge sorted-asc T(8) with sorted-asc S(8): keep 8 smallest sorted in T
#define MERGE8D(T, S) {                                                        \
    double t[KK];                                                              \
    t[0] = fmin(T[0], S[7]);  t[1] = fmin(T[1], S[6]);                         \
    t[2] = fmin(T[2], S[5]);  t[3] = fmin(T[3], S[4]);                         \
    t[4] = fmin(T[4], S[3]);  t[5] = fmin(T[5], S[2]);                         \
    t[6] = fmin(T[6], S[1]);  t[7] = fmin(T[7], S[0]);                         \
    CLEAN8D(t)                                                                 \
    T[0]=t[0]; T[1]=t[1]; T[2]=t[2]; T[3]=t[3];                                \
    T[4]=t[4]; T[5]=t[5]; T[6]=t[6]; T[7]=t[7]; }

// 32 lanes per query row, 2 rows per wave, 8 strided rows per block.
// Single 40 KB LDS window (all 2048 candidates), masks folded into staging.
__global__ __launch_bounds__(256, 4)
void knn_topk_kernel(const float* __restrict__ coords,   // [B,V,S] f32
                     const float* __restrict__ feats,    // [B,V,F] f32
                     const float* __restrict__ active,   // [B,1]   f32
                     float* __restrict__ out_dist,       // [B,V,K-1]
                     float* __restrict__ out_feat)       // [B,V,K-1,F]
{
#pragma clang fp contract(off)
    __shared__ float4 sc[VV];   // 32 KB: -2*c for all candidates
    __shared__ float  sn[VV];   //  8 KB: norm, or FLT_MAX where w >= Ai

    const int b   = blockIdx.y;
    const int tid = threadIdx.x;
    const int l   = tid & 31;              // lane within 32-lane row-group
    const int j   = tid >> 5;              // row slot 0..7
    const int v   = blockIdx.x + (j << 8); // strided rows: perfect balance

    const float A = active[b];
    int Ai = (int)ceilf(A);
    Ai = Ai < 0 ? 0 : (Ai > VV ? VV : Ai);

    const size_t row = (size_t)b * VV + v;
    const float4* cg = reinterpret_cast<const float4*>(coords + (size_t)b * VV * SS);

    const bool rowActive = ((float)v < A);
    const bool heavy = (__ballot(rowActive) != 0ULL);   // wave-uniform

    const float4 cv = cg[v];
    float qp0 = cv.x*cv.x, qp1 = cv.y*cv.y, qp2 = cv.z*cv.z, qp3 = cv.w*cv.w;
    const float nv  = ((qp0 + qp1) + qp2) + qp3;
    const float nvp = rowActive ? nv : FLT_MAX;   // v-mask folded into nv

    // running top-8, sorted ascending, f64-packed (dist, idx) keys
    double top[KK];
#pragma unroll
    for (int i = 0; i < KK; ++i)
        top[i] = __longlong_as_double((long long)(KEY_BIAS | 0xFFFFFFFFFFFFFULL));

    const int ntiles = (Ai + 31) >> 5;           // candidate tiles (32 wide)
    int nb = (ntiles + 15) >> 4;                 // batches of 16 tiles
    if (nb < 1) nb = 1;                          // >=16 keys/lane, all semantic

    // ---- stage all candidates once: -2c, and norm with w-mask folded in ----
    for (int i = tid; i < VV; i += 256) {
        const float4 c = cg[i];
        float p0 = c.x*c.x, p1 = c.y*c.y, p2 = c.z*c.z, p3 = c.w*c.w;
        const float nrm = ((p0 + p1) + p2) + p3;
        sn[i] = (i < Ai) ? nrm : FLT_MAX;        // masked => dist==FLT_MAX exact
        float4 c2;
        c2.x = -2.0f*c.x; c2.y = -2.0f*c.y;
        c2.z = -2.0f*c.z; c2.w = -2.0f*c.w;      // exact scaling
        sc[i] = c2;
    }
    __syncthreads();

    // ---- trivial rows: top-8 of an all-masked row = indices 0..7 ----
    if (!heavy) {
        if (l >= 1 && l < KK)
            __builtin_nontemporal_store(BF16_SAFE_MAX,
                                        &out_dist[row * (KK - 1) + (l - 1)]);
#pragma unroll
        for (int r = 1; r < KK; ++r) {
            const float2 val = reinterpret_cast<const float2*>(
                feats + ((size_t)b * VV + r) * FF)[l];
            nt_store_f2(out_feat + (row * (KK - 1) + (r - 1)) * FF + 2 * l, val);
        }
        return;
    }

#define SCAN_BATCH(M)                                                          \
    {                                                                          \
        const int bt = (M) << 4;                                               \
        double bk[16];                                                         \
        _Pragma("unroll")                                                      \
        for (int k = 0; k < 16; ++k) {                                         \
            const int w = ((bt + k) << 5) + l;                                 \
            const float4 cw = sc[w];                                           \
            const float  nw = sn[w];                                           \
            float q0 = cv.x*cw.x, q1 = cv.y*cw.y,                              \
                  q2 = cv.z*cw.z, q3 = cv.w*cw.w;                              \
            float dotp = ((q0 + q1) + q2) + q3;   /* == -2*dot bitwise */      \
            float sd = dotp + nvp;                                             \
            sd = sd + nw;                                                      \
            sd = fabsf(sd);                      /* FLT_MAX/inf if masked */   \
            bk[k] = mk_key(sd, (u32)w);                                        \
        }                                                                      \
        SORT8D(bk, 0)                                                          \
        SORT8D(bk, 8)                                                          \
        double s8[KK];                     /* 8 smallest of 16, sorted */      \
        s8[0] = fmin(bk[0], bk[15]); s8[1] = fmin(bk[1], bk[14]);              \
        s8[2] = fmin(bk[2], bk[13]); s8[3] = fmin(bk[3], bk[12]);              \
        s8[4] = fmin(bk[4], bk[11]); s8[5] = fmin(bk[5], bk[10]);              \
        s8[6] = fmin(bk[6], bk[9]);  s8[7] = fmin(bk[7], bk[8]);               \
        CLEAN8D(s8)                                                            \
        MERGE8D(top, s8)                                                       \
    }

    for (int m = 0; m < nb; ++m) SCAN_BATCH(m)
#undef SCAN_BATCH

    // ---- 5-level truncated bitonic merge across the 32-lane group ----
#pragma unroll
    for (int step = 1; step < 32; step <<= 1) {
        double t[KK];
#pragma unroll
        for (int i = 0; i < KK; ++i) {
            double pb = shfl_xor_f64(top[KK - 1 - i], step);
            t[i] = fmin(top[i], pb);
        }
        CLEAN8D(t)
#pragma unroll
        for (int i = 0; i < KK; ++i) top[i] = t[i];
    }
    // all 32 lanes hold the row's top-8 ascending; rank 0 = self/dropped

    // ---- epilogue ----
    u32 kd = 0;
#pragma unroll
    for (int r = 1; r < KK; ++r) kd = (l == r) ? key_dist(top[r]) : kd;
    if (l >= 1 && l < KK) {
        float d = __uint_as_float(kd);
        if (!(d <= BF16_SAFE_MAX)) d = BF16_SAFE_MAX;  // finite in bf16; kills inf
        __builtin_nontemporal_store(d, &out_dist[row * (KK - 1) + (l - 1)]);
    }

#pragma unroll
    for (int r = 1; r < KK; ++r) {
        const u32 idx = key_idx(top[r]);
        const float2 val = reinterpret_cast<const float2*>(
            feats + ((size_t)b * VV + idx) * FF)[l];
        nt_store_f2(out_feat + (row * (KK - 1) + (r - 1)) * FF + 2 * l, val);
    }
}

extern "C" void kernel_launch(void* const* d_in, const int* in_sizes, int n_in,
                              void* d_out, int out_size, void* d_ws, size_t ws_size,
                              hipStream_t stream)
{
    const float* coords = (const float*)d_in[0];
    const float* feats  = (const float*)d_in[1];
    const float* act    = (const float*)d_in[2];
    float* out_dist = (float*)d_out;
    float* out_feat = out_dist + (size_t)BB * VV * (KK - 1);

    dim3 grid(VV / 8, BB);    // 2048 blocks, 8 strided rows each
    knn_topk_kernel<<<grid, dim3(256), 0, stream>>>(coords, feats, act,
                                                    out_dist, out_feat);
}

// Round 14
// 27.468 us; speedup vs baseline: 1.1073x; 1.1073x over previous
//
#include <hip/hip_runtime.h>
#include <cstdint>
#include <cfloat>
#include <cstddef>

#define BB 8
#define VV 2048
#define SS 4
#define FF 64
#define KK 8

// Largest f32 that stays FINITE when rounded to bf16 (FLT_MAX -> bf16 = +inf).
#define BF16_SAFE_MAX 3.3e38f

typedef unsigned long long u64;
typedef unsigned int u32;

// ---- f64-packed keys: value order == (dist_bits, index) lexicographic ----
// bits = (1<<62) | (dist_bits << 20) | w -> normal positive double, never NaN.
// dist_bits may be FLT_MAX (masked == ref MAX_DIST, bit-exact) or +inf
// (double-masked); both sort after real keys and among themselves by index,
// which is exactly the reference's stable tie-break.
#define KEY_BIAS (1ULL << 62)

static __forceinline__ __device__ double mk_key(float d, u32 w) {
    return __longlong_as_double(
        (long long)(KEY_BIAS | ((u64)__float_as_uint(d) << 20) | (u64)w));
}
static __forceinline__ __device__ u32 key_dist(double k) {
    return (u32)(((u64)__double_as_longlong(k)) >> 20);
}
static __forceinline__ __device__ u32 key_idx(double k) {
    return (u32)((u64)__double_as_longlong(k) & (u64)(VV - 1));
}
static __forceinline__ __device__ double shfl_xor_f64(double x, int m) {
    const u64 b = (u64)__double_as_longlong(x);
    int lo = __shfl_xor((int)(u32)b, m, 64);
    int hi = __shfl_xor((int)(u32)(b >> 32), m, 64);
    return __longlong_as_double((long long)(((u64)(u32)hi << 32) | (u32)lo));
}

#define CED(A, x, y) { double lo_ = fmin(A[x], A[y]);                          \
                       double hi_ = fmax(A[x], A[y]);                          \
                       A[x] = lo_; A[y] = hi_; }

// Batcher odd-even mergesort, n=8, 19 comparators, on A[O..O+7]
#define SORT8D(K, O)                                                           \
    CED(K,O+0,O+1) CED(K,O+2,O+3) CED(K,O+4,O+5) CED(K,O+6,O+7)                \
    CED(K,O+0,O+2) CED(K,O+1,O+3) CED(K,O+4,O+6) CED(K,O+5,O+7)                \
    CED(K,O+1,O+2) CED(K,O+5,O+6)                                              \
    CED(K,O+0,O+4) CED(K,O+1,O+5) CED(K,O+2,O+6) CED(K,O+3,O+7)                \
    CED(K,O+2,O+4) CED(K,O+3,O+5)                                              \
    CED(K,O+1,O+2) CED(K,O+3,O+4) CED(K,O+5,O+6)

// bitonic clean of t[0..7] (strides 4,2,1)
#define CLEAN8D(t)                                                             \
    CED(t,0,4) CED(t,1,5) CED(t,2,6) CED(t,3,7)                                \
    CED(t,0,2) CED(t,1,3) CED(t,4,6) CED(t,5,7)                                \
    CED(t,0,1) CED(t,2,3) CED(t,4,5) CED(t,6,7)

// merge sorted-asc T(8) with sorted-asc S(8): keep 8 smallest sorted in T
#define MERGE8D(T, S) {                                                        \
    double t[KK];                                                              \
    t[0] = fmin(T[0], S[7]);  t[1] = fmin(T[1], S[6]);                         \
    t[2] = fmin(T[2], S[5]);  t[3] = fmin(T[3], S[4]);                         \
    t[4] = fmin(T[4], S[3]);  t[5] = fmin(T[5], S[2]);                         \
    t[6] = fmin(T[6], S[1]);  t[7] = fmin(T[7], S[0]);                         \
    CLEAN8D(t)                                                                 \
    T[0]=t[0]; T[1]=t[1]; T[2]=t[2]; T[3]=t[3];                                \
    T[4]=t[4]; T[5]=t[5]; T[6]=t[6]; T[7]=t[7]; }

// 32 lanes per query row, 2 rows per wave, 8 strided rows per block.
// Two-pass 20 KB LDS staging; mask folded into staged norms (no per-cand mask).
__global__ __launch_bounds__(256, 6)
void knn_topk_kernel(const float* __restrict__ coords,   // [B,V,S] f32
                     const float* __restrict__ feats,    // [B,V,F] f32
                     const float* __restrict__ active,   // [B,1]   f32
                     float* __restrict__ out_dist,       // [B,V,K-1]
                     float* __restrict__ out_feat)       // [B,V,K-1,F]
{
#pragma clang fp contract(off)
    __shared__ float4 sc[VV / 2];   // 16 KB: -2*c for one half-range
    __shared__ float  sn[VV / 2];   //  4 KB: norm, or FLT_MAX where masked

    const int b   = blockIdx.y;
    const int tid = threadIdx.x;
    const int l   = tid & 31;              // lane within 32-lane row-group
    const int j   = tid >> 5;              // row slot 0..7
    const int v   = blockIdx.x + (j << 8); // strided rows: perfect balance

    const float A = active[b];
    int Ai = (int)ceilf(A);
    Ai = Ai < 0 ? 0 : (Ai > VV ? VV : Ai);

    const size_t row = (size_t)b * VV + v;
    const float4* cg = reinterpret_cast<const float4*>(coords + (size_t)b * VV * SS);

    const bool rowActive = ((float)v < A);
    const bool heavy = (__ballot(rowActive) != 0ULL);   // wave-uniform

    const float4 cv = cg[v];
    float qp0 = cv.x*cv.x, qp1 = cv.y*cv.y, qp2 = cv.z*cv.z, qp3 = cv.w*cv.w;
    const float nv  = ((qp0 + qp1) + qp2) + qp3;
    const float nvp = rowActive ? nv : FLT_MAX;   // v-mask folded into nv

    // running top-8, sorted ascending, f64-packed (dist, idx) keys
    double top[KK];
#pragma unroll
    for (int i = 0; i < KK; ++i)
        top[i] = __longlong_as_double((long long)(KEY_BIAS | 0xFFFFFFFFFFFFFULL));

    int ntiles = (Ai + 31) >> 5;                 // candidate tiles (32 wide)
    if (ntiles < 16) ntiles = 16;                // >=16 keys/lane (all semantic)
    const int nb  = (ntiles + 15) >> 4;          // batches of 16 tiles, 1..4
    const int nb1 = nb < 2 ? nb : 2;             // pass-1 batches (w < 1024)

// stage -2*c and masked norm for half-range P (global index i + P*1024)
#define STAGE(P)                                                               \
    for (int i = tid; i < VV / 2; i += 256) {                                  \
        const float4 c = cg[i + ((P) << 10)];                                  \
        float p0 = c.x*c.x, p1 = c.y*c.y, p2 = c.z*c.z, p3 = c.w*c.w;          \
        const float nrm = ((p0 + p1) + p2) + p3;                               \
        sn[i] = ((i + ((P) << 10)) < Ai) ? nrm : FLT_MAX;                      \
        float4 c2;                                                             \
        c2.x = -2.0f*c.x; c2.y = -2.0f*c.y;                                    \
        c2.z = -2.0f*c.z; c2.w = -2.0f*c.w;     /* exact scaling */            \
        sc[i] = c2;                                                            \
    }

// uniform scan: no per-candidate masking (folded into sn / nvp)
#define SCAN_BATCH(M)                                                          \
    {                                                                          \
        const int bt = (M) << 4;                                               \
        double bk[16];                                                         \
        _Pragma("unroll")                                                      \
        for (int k = 0; k < 16; ++k) {                                         \
            const int w  = ((bt + k) << 5) + l;                                \
            const int wi = w & (VV / 2 - 1);                                   \
            const float4 cw = sc[wi];                                          \
            const float  nw = sn[wi];                                          \
            float q0 = cv.x*cw.x, q1 = cv.y*cw.y,                              \
                  q2 = cv.z*cw.z, q3 = cv.w*cw.w;                              \
            float dotp = ((q0 + q1) + q2) + q3;   /* == -2*dot bitwise */      \
            float sd = dotp + nvp;                                             \
            sd = sd + nw;                                                      \
            sd = fabsf(sd);                      /* FLT_MAX/inf if masked */   \
            bk[k] = mk_key(sd, (u32)w);                                        \
        }                                                                      \
        SORT8D(bk, 0)                                                          \
        SORT8D(bk, 8)                                                          \
        double s8[KK];                     /* 8 smallest of 16, sorted */      \
        s8[0] = fmin(bk[0], bk[15]); s8[1] = fmin(bk[1], bk[14]);              \
        s8[2] = fmin(bk[2], bk[13]); s8[3] = fmin(bk[3], bk[12]);              \
        s8[4] = fmin(bk[4], bk[11]); s8[5] = fmin(bk[5], bk[10]);              \
        s8[6] = fmin(bk[6], bk[9]);  s8[7] = fmin(bk[7], bk[8]);               \
        CLEAN8D(s8)                                                            \
        MERGE8D(top, s8)                                                       \
    }

    // ---- pass 1: candidates w in [0, 1024) ----
    STAGE(0)
    __syncthreads();
    if (heavy) {
        for (int m = 0; m < nb1; ++m) SCAN_BATCH(m)
    }

    // ---- pass 2: candidates w in [1024, 2048) ----
    if (nb > 2) {
        __syncthreads();          // everyone done reading pass-1 LDS
        STAGE(1)
        __syncthreads();
        if (heavy) {
            for (int m = 2; m < nb; ++m) SCAN_BATCH(m)
        }
    }
#undef STAGE
#undef SCAN_BATCH

    // ---- trivial rows: top-8 of an all-masked row = indices 0..7 ----
    if (!heavy) {
        if (l >= 1 && l < KK)
            out_dist[row * (KK - 1) + (l - 1)] = BF16_SAFE_MAX;
#pragma unroll
        for (int r = 1; r < KK; ++r) {
            const float2 val = reinterpret_cast<const float2*>(
                feats + ((size_t)b * VV + r) * FF)[l];
            reinterpret_cast<float2*>(out_feat + (row * (KK - 1) + (r - 1)) * FF)[l] = val;
        }
        return;
    }

    // ---- 5-level truncated bitonic merge across the 32-lane group ----
#pragma unroll
    for (int step = 1; step < 32; step <<= 1) {
        double t[KK];
#pragma unroll
        for (int i = 0; i < KK; ++i) {
            double pb = shfl_xor_f64(top[KK - 1 - i], step);
            t[i] = fmin(top[i], pb);
        }
        CLEAN8D(t)
#pragma unroll
        for (int i = 0; i < KK; ++i) top[i] = t[i];
    }
    // all 32 lanes hold the row's top-8 ascending; rank 0 = self/dropped

    // ---- epilogue ----
    u32 kd = 0;
#pragma unroll
    for (int r = 1; r < KK; ++r) kd = (l == r) ? key_dist(top[r]) : kd;
    if (l >= 1 && l < KK) {
        float d = __uint_as_float(kd);
        if (!(d <= BF16_SAFE_MAX)) d = BF16_SAFE_MAX;  // finite in bf16; kills inf
        out_dist[row * (KK - 1) + (l - 1)] = d;
    }

#pragma unroll
    for (int r = 1; r < KK; ++r) {
        const u32 idx = key_idx(top[r]);
        const float2 val = reinterpret_cast<const float2*>(
            feats + ((size_t)b * VV + idx) * FF)[l];
        reinterpret_cast<float2*>(out_feat + (row * (KK - 1) + (r - 1)) * FF)[l] = val;
    }
}

extern "C" void kernel_launch(void* const* d_in, const int* in_sizes, int n_in,
                              void* d_out, int out_size, void* d_ws, size_t ws_size,
                              hipStream_t stream)
{
    const float* coords = (const float*)d_in[0];
    const float* feats  = (const float*)d_in[1];
    const float* act    = (const float*)d_in[2];
    float* out_dist = (float*)d_out;
    float* out_feat = out_dist + (size_t)BB * VV * (KK - 1);

    dim3 grid(VV / 8, BB);    // 2048 blocks, 8 strided rows each
    knn_topk_kernel<<<grid, dim3(256), 0, stream>>>(coords, feats, act,
                                                    out_dist, out_feat);
}

// Round 15
// 26.563 us; speedup vs baseline: 1.1451x; 1.0341x over previous
//
#include <hip/hip_runtime.h>
#include <cstdint>
#include <cfloat>
#include <cstddef>

#define BB 8
#define VV 2048
#define SS 4
#define FF 64
#define KK 8

// Largest f32 that stays FINITE when rounded to bf16 (FLT_MAX -> bf16 = +inf).
#define BF16_SAFE_MAX 3.3e38f

typedef unsigned long long u64;
typedef unsigned int u32;

// ---- cvt-packed f64 keys ----
// key = bits((double)sd) | w, sd in [0, FLT_MAX] (clamped), w < 2048.
// (double)sd is exact with 29 zero low mantissa bits; OR-ing the 11-bit index
// preserves strict (dist, idx) lexicographic order for positive doubles
// (distinct f32 dists differ at bit >= 29 >> 2047). (float)key rounds back to
// exactly sd (index perturbation << 0.5 ulp_f32). No NaN/inf possible after
// the FLT_MAX clamp. fmin/fmax = 2-instruction CE with the index embedded.
static __forceinline__ __device__ double mk_key(float sd_clamped, u32 w) {
    return __longlong_as_double(
        __double_as_longlong((double)sd_clamped) | (long long)w);
}
static __forceinline__ __device__ u32 key_idx(double k) {
    return (u32)((u64)__double_as_longlong(k) & (u64)(VV - 1));
}
static __forceinline__ __device__ double shfl_xor_f64(double x, int m) {
    const u64 b = (u64)__double_as_longlong(x);
    int lo = __shfl_xor((int)(u32)b, m, 64);
    int hi = __shfl_xor((int)(u32)(b >> 32), m, 64);
    return __longlong_as_double((long long)(((u64)(u32)hi << 32) | (u32)lo));
}

#define CED(A, x, y) { double lo_ = fmin(A[x], A[y]);                          \
                       double hi_ = fmax(A[x], A[y]);                          \
                       A[x] = lo_; A[y] = hi_; }

// Batcher odd-even mergesort, n=8, 19 comparators, on A[O..O+7]
#define SORT8D(K, O)                                                           \
    CED(K,O+0,O+1) CED(K,O+2,O+3) CED(K,O+4,O+5) CED(K,O+6,O+7)                \
    CED(K,O+0,O+2) CED(K,O+1,O+3) CED(K,O+4,O+6) CED(K,O+5,O+7)                \
    CED(K,O+1,O+2) CED(K,O+5,O+6)                                              \
    CED(K,O+0,O+4) CED(K,O+1,O+5) CED(K,O+2,O+6) CED(K,O+3,O+7)                \
    CED(K,O+2,O+4) CED(K,O+3,O+5)                                              \
    CED(K,O+1,O+2) CED(K,O+3,O+4) CED(K,O+5,O+6)

// bitonic clean of t[0..7] (strides 4,2,1)
#define CLEAN8D(t)                                                             \
    CED(t,0,4) CED(t,1,5) CED(t,2,6) CED(t,3,7)                                \
    CED(t,0,2) CED(t,1,3) CED(t,4,6) CED(t,5,7)                                \
    CED(t,0,1) CED(t,2,3) CED(t,4,5) CED(t,6,7)

// merge sorted-asc T(8) with sorted-asc S(8): keep 8 smallest sorted in T
#define MERGE8D(T, S) {                                                        \
    double t[KK];                                                              \
    t[0] = fmin(T[0], S[7]);  t[1] = fmin(T[1], S[6]);                         \
    t[2] = fmin(T[2], S[5]);  t[3] = fmin(T[3], S[4]);                         \
    t[4] = fmin(T[4], S[3]);  t[5] = fmin(T[5], S[2]);                         \
    t[6] = fmin(T[6], S[1]);  t[7] = fmin(T[7], S[0]);                         \
    CLEAN8D(t)                                                                 \
    T[0]=t[0]; T[1]=t[1]; T[2]=t[2]; T[3]=t[3];                                \
    T[4]=t[4]; T[5]=t[5]; T[6]=t[6]; T[7]=t[7]; }

// compute batch M's sorted 8-smallest-of-16 into S8 (keys fully semantic:
// masked candidates carry FLT_MAX == ref MAX_DIST, tie-broken by index)
#define BATCH_S8(M, S8)                                                        \
    {                                                                          \
        const int bt = (M) << 4;                                               \
        double bk[16];                                                         \
        _Pragma("unroll")                                                      \
        for (int k = 0; k < 16; ++k) {                                         \
            const int w  = ((bt + k) << 5) + l;                                \
            const int wi = w & (VV / 2 - 1);                                   \
            const float4 cw = sc[wi];                                          \
            const float  nw = sn[wi];                                          \
            float q0 = cv.x*cw.x, q1 = cv.y*cw.y,                              \
                  q2 = cv.z*cw.z, q3 = cv.w*cw.w;                              \
            float dotp = ((q0 + q1) + q2) + q3;   /* == -2*dot bitwise */      \
            float sd = dotp + nvp;                                             \
            sd = sd + nw;                                                      \
            const float sda = fminf(fabsf(sd), FLT_MAX); /* 1 VOP3: |x| mod */ \
            bk[k] = mk_key(sda, (u32)w);                                       \
        }                                                                      \
        SORT8D(bk, 0)                                                          \
        SORT8D(bk, 8)                                                          \
        S8[0] = fmin(bk[0], bk[15]); S8[1] = fmin(bk[1], bk[14]);              \
        S8[2] = fmin(bk[2], bk[13]); S8[3] = fmin(bk[3], bk[12]);              \
        S8[4] = fmin(bk[4], bk[11]); S8[5] = fmin(bk[5], bk[10]);              \
        S8[6] = fmin(bk[6], bk[9]);  S8[7] = fmin(bk[7], bk[8]);               \
        CLEAN8D(S8)                                                            \
    }

// 32 lanes per query row, 2 rows per wave, 8 strided rows per block.
// Two-pass 20 KB LDS staging; masks folded into staged norms; cvt-packed keys.
__global__ __launch_bounds__(256, 6)
void knn_topk_kernel(const float* __restrict__ coords,   // [B,V,S] f32
                     const float* __restrict__ feats,    // [B,V,F] f32
                     const float* __restrict__ active,   // [B,1]   f32
                     float* __restrict__ out_dist,       // [B,V,K-1]
                     float* __restrict__ out_feat)       // [B,V,K-1,F]
{
#pragma clang fp contract(off)
    __shared__ float4 sc[VV / 2];   // 16 KB: -2*c for one half-range
    __shared__ float  sn[VV / 2];   //  4 KB: norm, or FLT_MAX where masked

    const int b   = blockIdx.y;
    const int tid = threadIdx.x;
    const int l   = tid & 31;              // lane within 32-lane row-group
    const int j   = tid >> 5;              // row slot 0..7
    const int v   = blockIdx.x + (j << 8); // strided rows: perfect balance

    const float A = active[b];
    int Ai = (int)ceilf(A);
    Ai = Ai < 0 ? 0 : (Ai > VV ? VV : Ai);

    const size_t row = (size_t)b * VV + v;
    const float4* cg = reinterpret_cast<const float4*>(coords + (size_t)b * VV * SS);

    const bool rowActive = ((float)v < A);
    const bool heavy = (__ballot(rowActive) != 0ULL);   // wave-uniform

    const float4 cv = cg[v];
    float qp0 = cv.x*cv.x, qp1 = cv.y*cv.y, qp2 = cv.z*cv.z, qp3 = cv.w*cv.w;
    const float nv  = ((qp0 + qp1) + qp2) + qp3;
    const float nvp = rowActive ? nv : FLT_MAX;   // v-mask folded into nv

    double top[KK];                 // running top-8, sorted asc (cvt-packed)

    int ntiles = (Ai + 31) >> 5;                 // candidate tiles (32 wide)
    if (ntiles < 16) ntiles = 16;                // keep batch geometry fixed
    const int nb  = (ntiles + 15) >> 4;          // batches of 16 tiles, 1..4
    const int nb1 = nb < 2 ? nb : 2;             // pass-1 batches (w < 1024)

// stage -2*c and masked norm for half-range P (global index i + P*1024)
#define STAGE(P)                                                               \
    for (int i = tid; i < VV / 2; i += 256) {                                  \
        const float4 c = cg[i + ((P) << 10)];                                  \
        float p0 = c.x*c.x, p1 = c.y*c.y, p2 = c.z*c.z, p3 = c.w*c.w;          \
        const float nrm = ((p0 + p1) + p2) + p3;                               \
        sn[i] = ((i + ((P) << 10)) < Ai) ? nrm : FLT_MAX;                      \
        float4 c2;                                                             \
        c2.x = -2.0f*c.x; c2.y = -2.0f*c.y;                                    \
        c2.z = -2.0f*c.z; c2.w = -2.0f*c.w;     /* exact scaling */            \
        sc[i] = c2;                                                            \
    }

    // ---- pass 1: candidates w in [0, 1024) ----
    STAGE(0)
    __syncthreads();
    if (heavy) {
        BATCH_S8(0, top)                          // peeled: batch 0 IS top
        for (int m = 1; m < nb1; ++m) {
            double s8[KK];
            BATCH_S8(m, s8)
            MERGE8D(top, s8)
        }
    }

    // ---- pass 2: candidates w in [1024, 2048) ----
    if (nb > 2) {
        __syncthreads();          // everyone done reading pass-1 LDS
        STAGE(1)
        __syncthreads();
        if (heavy) {
            for (int m = 2; m < nb; ++m) {
                double s8[KK];
                BATCH_S8(m, s8)
                MERGE8D(top, s8)
            }
        }
    }
#undef STAGE

    // ---- trivial rows: top-8 of an all-masked row = indices 0..7 ----
    if (!heavy) {
        if (l >= 1 && l < KK)
            out_dist[row * (KK - 1) + (l - 1)] = BF16_SAFE_MAX;
#pragma unroll
        for (int r = 1; r < KK; ++r) {
            const float2 val = reinterpret_cast<const float2*>(
                feats + ((size_t)b * VV + r) * FF)[l];
            reinterpret_cast<float2*>(out_feat + (row * (KK - 1) + (r - 1)) * FF)[l] = val;
        }
        return;
    }

    // ---- 5-level truncated bitonic merge across the 32-lane group ----
#pragma unroll
    for (int step = 1; step < 32; step <<= 1) {
        double t[KK];
#pragma unroll
        for (int i = 0; i < KK; ++i) {
            double pb = shfl_xor_f64(top[KK - 1 - i], step);
            t[i] = fmin(top[i], pb);
        }
        CLEAN8D(t)
#pragma unroll
        for (int i = 0; i < KK; ++i) top[i] = t[i];
    }
    // all 32 lanes hold the row's top-8 ascending; rank 0 = self/dropped

    // ---- epilogue ----
    float dsel = 0.0f;
#pragma unroll
    for (int r = 1; r < KK; ++r) dsel = (l == r) ? (float)top[r] : dsel;
    if (l >= 1 && l < KK) {
        float d = dsel;           // exact f32 distance (cvt rounds back exactly)
        if (!(d <= BF16_SAFE_MAX)) d = BF16_SAFE_MAX;  // finite under bf16
        out_dist[row * (KK - 1) + (l - 1)] = d;
    }

#pragma unroll
    for (int r = 1; r < KK; ++r) {
        const u32 idx = key_idx(top[r]);
        const float2 val = reinterpret_cast<const float2*>(
            feats + ((size_t)b * VV + idx) * FF)[l];
        reinterpret_cast<float2*>(out_feat + (row * (KK - 1) + (r - 1)) * FF)[l] = val;
    }
}

extern "C" void kernel_launch(void* const* d_in, const int* in_sizes, int n_in,
                              void* d_out, int out_size, void* d_ws, size_t ws_size,
                              hipStream_t stream)
{
    const float* coords = (const float*)d_in[0];
    const float* feats  = (const float*)d_in[1];
    const float* act    = (const float*)d_in[2];
    float* out_dist = (float*)d_out;
    float* out_feat = out_dist + (size_t)BB * VV * (KK - 1);

    dim3 grid(VV / 8, BB);    // 2048 blocks, 8 strided rows each
    knn_topk_kernel<<<grid, dim3(256), 0, stream>>>(coords, feats, act,
                                                    out_dist, out_feat);
}

// Round 16
// 25.860 us; speedup vs baseline: 1.1762x; 1.0272x over previous
//
#include <hip/hip_runtime.h>
#include <cstdint>
#include <cfloat>
#include <cstddef>

#define BB 8
#define VV 2048
#define SS 4
#define FF 64
#define KK 8

// Largest f32 that stays FINITE when rounded to bf16 (FLT_MAX -> bf16 = +inf).
#define BF16_SAFE_MAX 3.3e38f

typedef unsigned long long u64;
typedef unsigned int u32;

// ---- cvt-packed f64 keys ----
// key = bits((double)sd) | w, sd in [0, FLT_MAX] (clamped), w < 2048.
// (double)sd is exact with 29 zero low mantissa bits; OR-ing the 11-bit index
// preserves strict (dist, idx) lexicographic order for positive doubles.
// (float)key rounds back to exactly sd. No NaN/inf after the FLT_MAX clamp.
// fmin/fmax (v_min_f64/v_max_f64) = 2-instruction CE with the index embedded.
static __forceinline__ __device__ double mk_key(float sd_clamped, u32 w) {
    return __longlong_as_double(
        __double_as_longlong((double)sd_clamped) | (long long)w);
}
static __forceinline__ __device__ u32 key_idx(double k) {
    return (u32)((u64)__double_as_longlong(k) & (u64)(VV - 1));
}
static __forceinline__ __device__ double shfl_xor_f64(double x, int m) {
    const u64 b = (u64)__double_as_longlong(x);
    int lo = __shfl_xor((int)(u32)b, m, 64);
    int hi = __shfl_xor((int)(u32)(b >> 32), m, 64);
    return __longlong_as_double((long long)(((u64)(u32)hi << 32) | (u32)lo));
}

#define CED(A, x, y) { double lo_ = fmin(A[x], A[y]);                          \
                       double hi_ = fmax(A[x], A[y]);                          \
                       A[x] = lo_; A[y] = hi_; }

// Batcher odd-even mergesort, n=8, 19 comparators, on A[O..O+7]
#define SORT8D(K, O)                                                           \
    CED(K,O+0,O+1) CED(K,O+2,O+3) CED(K,O+4,O+5) CED(K,O+6,O+7)                \
    CED(K,O+0,O+2) CED(K,O+1,O+3) CED(K,O+4,O+6) CED(K,O+5,O+7)                \
    CED(K,O+1,O+2) CED(K,O+5,O+6)                                              \
    CED(K,O+0,O+4) CED(K,O+1,O+5) CED(K,O+2,O+6) CED(K,O+3,O+7)                \
    CED(K,O+2,O+4) CED(K,O+3,O+5)                                              \
    CED(K,O+1,O+2) CED(K,O+3,O+4) CED(K,O+5,O+6)

// bitonic clean of t[0..7] (strides 4,2,1)
#define CLEAN8D(t)                                                             \
    CED(t,0,4) CED(t,1,5) CED(t,2,6) CED(t,3,7)                                \
    CED(t,0,2) CED(t,1,3) CED(t,4,6) CED(t,5,7)                                \
    CED(t,0,1) CED(t,2,3) CED(t,4,5) CED(t,6,7)

// merge sorted-asc T(8) with sorted-asc S(8): keep 8 smallest sorted in T
#define MERGE8D(T, S) {                                                        \
    double t[KK];                                                              \
    t[0] = fmin(T[0], S[7]);  t[1] = fmin(T[1], S[6]);                         \
    t[2] = fmin(T[2], S[5]);  t[3] = fmin(T[3], S[4]);                         \
    t[4] = fmin(T[4], S[3]);  t[5] = fmin(T[5], S[2]);                         \
    t[6] = fmin(T[6], S[1]);  t[7] = fmin(T[7], S[0]);                         \
    CLEAN8D(t)                                                                 \
    T[0]=t[0]; T[1]=t[1]; T[2]=t[2]; T[3]=t[3];                                \
    T[4]=t[4]; T[5]=t[5]; T[6]=t[6]; T[7]=t[7]; }

// batch M (LITERAL 0..3): sorted 8-smallest-of-16 into S8.
// With M literal, w = l + CONST and the LDS index const-folds -> ds_read with
// immediate offsets off a once-computed lane base. Keys fully semantic
// (masked candidates carry FLT_MAX == ref MAX_DIST, tie-broken by index).
#define BATCH_S8(M, S8)                                                        \
    {                                                                          \
        double bk[16];                                                         \
        _Pragma("unroll")                                                      \
        for (int k = 0; k < 16; ++k) {                                         \
            const int w  = (((M) << 4) + k) * 32 + l;      /* l + CONST */     \
            const int wi = w & (VV / 2 - 1);               /* const-folds */   \
            const float4 cw = sc[wi];                                          \
            const float  nw = sn[wi];                                          \
            float q0 = cv.x*cw.x, q1 = cv.y*cw.y,                              \
                  q2 = cv.z*cw.z, q3 = cv.w*cw.w;                              \
            float dotp = ((q0 + q1) + q2) + q3;   /* == -2*dot bitwise */      \
            float sd = dotp + nvp;                                             \
            sd = sd + nw;                                                      \
            const float sda = fminf(fabsf(sd), FLT_MAX);                       \
            bk[k] = mk_key(sda, (u32)w);                                       \
        }                                                                      \
        SORT8D(bk, 0)                                                          \
        SORT8D(bk, 8)                                                          \
        S8[0] = fmin(bk[0], bk[15]); S8[1] = fmin(bk[1], bk[14]);              \
        S8[2] = fmin(bk[2], bk[13]); S8[3] = fmin(bk[3], bk[12]);              \
        S8[4] = fmin(bk[4], bk[11]); S8[5] = fmin(bk[5], bk[10]);              \
        S8[6] = fmin(bk[6], bk[9]);  S8[7] = fmin(bk[7], bk[8]);               \
        CLEAN8D(S8)                                                            \
    }

// 32 lanes per query row, 2 rows per wave, 8 strided rows per block.
// Two-pass 20 KB LDS staging; masks folded into staged norms; static batches.
__global__ __launch_bounds__(256, 6)
void knn_topk_kernel(const float* __restrict__ coords,   // [B,V,S] f32
                     const float* __restrict__ feats,    // [B,V,F] f32
                     const float* __restrict__ active,   // [B,1]   f32
                     float* __restrict__ out_dist,       // [B,V,K-1]
                     float* __restrict__ out_feat)       // [B,V,K-1,F]
{
#pragma clang fp contract(off)
    __shared__ float4 sc[VV / 2];   // 16 KB: -2*c for one half-range
    __shared__ float  sn[VV / 2];   //  4 KB: norm, or FLT_MAX where masked

    const int b   = blockIdx.y;
    const int tid = threadIdx.x;
    const int l   = tid & 31;              // lane within 32-lane row-group
    const int j   = tid >> 5;              // row slot 0..7
    const int v   = blockIdx.x + (j << 8); // strided rows: perfect balance

    const float A = active[b];
    int Ai = (int)ceilf(A);
    Ai = Ai < 0 ? 0 : (Ai > VV ? VV : Ai);

    const size_t row = (size_t)b * VV + v;
    const float4* cg = reinterpret_cast<const float4*>(coords + (size_t)b * VV * SS);

    const bool rowActive = ((float)v < A);
    const bool heavy = (__ballot(rowActive) != 0ULL);   // wave-uniform

    const float4 cv = cg[v];
    float qp0 = cv.x*cv.x, qp1 = cv.y*cv.y, qp2 = cv.z*cv.z, qp3 = cv.w*cv.w;
    const float nv  = ((qp0 + qp1) + qp2) + qp3;
    const float nvp = rowActive ? nv : FLT_MAX;   // v-mask folded into nv

    double top[KK];                 // running top-8, sorted asc (cvt-packed)

    int ntiles = (Ai + 31) >> 5;                 // candidate tiles (32 wide)
    if (ntiles < 16) ntiles = 16;                // keep batch geometry fixed
    const int nb = (ntiles + 15) >> 4;           // batches of 16 tiles, 1..4

// stage -2*c and masked norm; LIM entries of half-range P
#define STAGE(P, LIM)                                                          \
    for (int i = tid; i < (LIM); i += 256) {                                   \
        const float4 c = cg[i + ((P) << 10)];                                  \
        float p0 = c.x*c.x, p1 = c.y*c.y, p2 = c.z*c.z, p3 = c.w*c.w;          \
        const float nrm = ((p0 + p1) + p2) + p3;                               \
        sn[i] = ((i + ((P) << 10)) < Ai) ? nrm : FLT_MAX;                      \
        float4 c2;                                                             \
        c2.x = -2.0f*c.x; c2.y = -2.0f*c.y;                                    \
        c2.z = -2.0f*c.z; c2.w = -2.0f*c.w;     /* exact scaling */            \
        sc[i] = c2;                                                            \
    }

    // ---- pass 1: candidates w in [0, 1024), batches 0..1 (static) ----
    STAGE(0, VV / 2)
    __syncthreads();
    if (heavy) {
        BATCH_S8(0, top)                          // peeled: batch 0 IS top
        if (nb > 1) {
            double s8[KK];
            BATCH_S8(1, s8)
            MERGE8D(top, s8)
        }
    }

    // ---- pass 2: candidates w in [1024, 2048), batches 2..3 (static) ----
    if (nb > 2) {
        const int lim2 = (nb << 9) - 1024;        // 512 (nb=3) or 1024 (nb=4)
        __syncthreads();          // everyone done reading pass-1 LDS
        STAGE(1, lim2)
        __syncthreads();
        if (heavy) {
            {
                double s8[KK];
                BATCH_S8(2, s8)
                MERGE8D(top, s8)
            }
            if (nb > 3) {
                double s8[KK];
                BATCH_S8(3, s8)
                MERGE8D(top, s8)
            }
        }
    }
#undef STAGE

    // ---- trivial rows: top-8 of an all-masked row = indices 0..7 ----
    if (!heavy) {
        if (l >= 1 && l < KK)
            out_dist[row * (KK - 1) + (l - 1)] = BF16_SAFE_MAX;
#pragma unroll
        for (int r = 1; r < KK; ++r) {
            const float2 val = reinterpret_cast<const float2*>(
                feats + ((size_t)b * VV + r) * FF)[l];
            reinterpret_cast<float2*>(out_feat + (row * (KK - 1) + (r - 1)) * FF)[l] = val;
        }
        return;
    }

    // ---- 5-level truncated bitonic merge across the 32-lane group ----
#pragma unroll
    for (int step = 1; step < 32; step <<= 1) {
        double t[KK];
#pragma unroll
        for (int i = 0; i < KK; ++i) {
            double pb = shfl_xor_f64(top[KK - 1 - i], step);
            t[i] = fmin(top[i], pb);
        }
        CLEAN8D(t)
#pragma unroll
        for (int i = 0; i < KK; ++i) top[i] = t[i];
    }
    // all 32 lanes hold the row's top-8 ascending; rank 0 = self/dropped

    // ---- epilogue ----
    float dsel = 0.0f;
#pragma unroll
    for (int r = 1; r < KK; ++r) dsel = (l == r) ? (float)top[r] : dsel;
    if (l >= 1 && l < KK) {
        float d = dsel;           // exact f32 distance (cvt rounds back exactly)
        if (!(d <= BF16_SAFE_MAX)) d = BF16_SAFE_MAX;  // finite under bf16
        out_dist[row * (KK - 1) + (l - 1)] = d;
    }

#pragma unroll
    for (int r = 1; r < KK; ++r) {
        const u32 idx = key_idx(top[r]);
        const float2 val = reinterpret_cast<const float2*>(
            feats + ((size_t)b * VV + idx) * FF)[l];
        reinterpret_cast<float2*>(out_feat + (row * (KK - 1) + (r - 1)) * FF)[l] = val;
    }
}

extern "C" void kernel_launch(void* const* d_in, const int* in_sizes, int n_in,
                              void* d_out, int out_size, void* d_ws, size_t ws_size,
                              hipStream_t stream)
{
    const float* coords = (const float*)d_in[0];
    const float* feats  = (const float*)d_in[1];
    const float* act    = (const float*)d_in[2];
    float* out_dist = (float*)d_out;
    float* out_feat = out_dist + (size_t)BB * VV * (KK - 1);

    dim3 grid(VV / 8, BB);    // 2048 blocks, 8 strided rows each
    knn_topk_kernel<<<grid, dim3(256), 0, stream>>>(coords, feats, act,
                                                    out_dist, out_feat);
}

// Round 17
// 24.276 us; speedup vs baseline: 1.2529x; 1.0653x over previous
//
#include <hip/hip_runtime.h>
#include <cstdint>
#include <cfloat>
#include <cstddef>

#define BB 8
#define VV 2048
#define SS 4
#define FF 64
#define KK 8

// Largest f32 that stays FINITE when rounded to bf16 (FLT_MAX -> bf16 = +inf).
#define BF16_SAFE_MAX 3.3e38f

typedef unsigned long long u64;
typedef unsigned int u32;

// ---- cvt-packed f64 keys ----
// key = bits((double)sd) | w, sd in [0, FLT_MAX] (clamped), w < 2048.
// (double)sd is exact with 29 zero low mantissa bits; OR-ing the 11-bit index
// preserves strict (dist, idx) lexicographic order for positive doubles.
// (float)key rounds back to exactly sd. No NaN/inf after the FLT_MAX clamp.
// fmin/fmax (v_min_f64/v_max_f64) = 2-instruction CE with the index embedded.
static __forceinline__ __device__ double mk_key(float sd_clamped, u32 w) {
    return __longlong_as_double(
        __double_as_longlong((double)sd_clamped) | (long long)w);
}
static __forceinline__ __device__ u32 key_idx(double k) {
    return (u32)((u64)__double_as_longlong(k) & (u64)(VV - 1));
}
static __forceinline__ __device__ double shfl_xor_f64(double x, int m) {
    const u64 b = (u64)__double_as_longlong(x);
    int lo = __shfl_xor((int)(u32)b, m, 64);
    int hi = __shfl_xor((int)(u32)(b >> 32), m, 64);
    return __longlong_as_double((long long)(((u64)(u32)hi << 32) | (u32)lo));
}

#define CED(A, x, y) { double lo_ = fmin(A[x], A[y]);                          \
                       double hi_ = fmax(A[x], A[y]);                          \
                       A[x] = lo_; A[y] = hi_; }

// Batcher odd-even mergesort, n=8, 19 comparators, on A[O..O+7]
#define SORT8D(K, O)                                                           \
    CED(K,O+0,O+1) CED(K,O+2,O+3) CED(K,O+4,O+5) CED(K,O+6,O+7)                \
    CED(K,O+0,O+2) CED(K,O+1,O+3) CED(K,O+4,O+6) CED(K,O+5,O+7)                \
    CED(K,O+1,O+2) CED(K,O+5,O+6)                                              \
    CED(K,O+0,O+4) CED(K,O+1,O+5) CED(K,O+2,O+6) CED(K,O+3,O+7)                \
    CED(K,O+2,O+4) CED(K,O+3,O+5)                                              \
    CED(K,O+1,O+2) CED(K,O+3,O+4) CED(K,O+5,O+6)

// bitonic clean of t[0..7] (strides 4,2,1)
#define CLEAN8D(t)                                                             \
    CED(t,0,4) CED(t,1,5) CED(t,2,6) CED(t,3,7)                                \
    CED(t,0,2) CED(t,1,3) CED(t,4,6) CED(t,5,7)                                \
    CED(t,0,1) CED(t,2,3) CED(t,4,5) CED(t,6,7)

// merge sorted-asc T(8) with sorted-asc S(8): keep 8 smallest sorted in T
#define MERGE8D(T, S) {                                                        \
    double t[KK];                                                              \
    t[0] = fmin(T[0], S[7]);  t[1] = fmin(T[1], S[6]);                         \
    t[2] = fmin(T[2], S[5]);  t[3] = fmin(T[3], S[4]);                         \
    t[4] = fmin(T[4], S[3]);  t[5] = fmin(T[5], S[2]);                         \
    t[6] = fmin(T[6], S[1]);  t[7] = fmin(T[7], S[0]);                         \
    CLEAN8D(t)                                                                 \
    T[0]=t[0]; T[1]=t[1]; T[2]=t[2]; T[3]=t[3];                                \
    T[4]=t[4]; T[5]=t[5]; T[6]=t[6]; T[7]=t[7]; }

// fill batch M (LITERAL 0..7) = tiles 8M..8M+7 into BK (8 keys, sorted after
// SORT8D). With M literal, w = l + CONST: LDS addressing const-folds to
// immediate offsets. Keys fully semantic (masked = FLT_MAX == ref MAX_DIST).
#define BATCH_FILL(M, BK)                                                      \
    {                                                                          \
        _Pragma("unroll")                                                      \
        for (int k = 0; k < 8; ++k) {                                          \
            const int w  = (((M) << 3) + k) * 32 + l;      /* l + CONST */     \
            const int wi = w & (VV / 2 - 1);               /* const-folds */   \
            const float4 cw = sc[wi];                                          \
            const float  nw = sn[wi];                                          \
            float q0 = cv.x*cw.x, q1 = cv.y*cw.y,                              \
                  q2 = cv.z*cw.z, q3 = cv.w*cw.w;                              \
            float dotp = ((q0 + q1) + q2) + q3;   /* == -2*dot bitwise */      \
            float sd = dotp + nvp;                                             \
            sd = sd + nw;                                                      \
            const float sda = fminf(fabsf(sd), FLT_MAX);                       \
            BK[k] = mk_key(sda, (u32)w);                                       \
        }                                                                      \
        SORT8D(BK, 0)                                                          \
    }

#define BATCH_MERGE(M)                                                         \
    {                                                                          \
        double bk[KK];                                                         \
        BATCH_FILL(M, bk)                                                      \
        MERGE8D(top, bk)                                                       \
    }

// 512 threads: 16 rows/block (32 lanes each), grid 1024 = 256 CU x 4 blocks
// -> single dispatch round at FULL thread occupancy (32 waves/CU).
// Two-pass 20 KB LDS staging; batch-8 scan (16 key VGPRs) fits the 64-reg cap.
__global__ __launch_bounds__(512, 8)
void knn_topk_kernel(const float* __restrict__ coords,   // [B,V,S] f32
                     const float* __restrict__ feats,    // [B,V,F] f32
                     const float* __restrict__ active,   // [B,1]   f32
                     float* __restrict__ out_dist,       // [B,V,K-1]
                     float* __restrict__ out_feat)       // [B,V,K-1,F]
{
#pragma clang fp contract(off)
    __shared__ float4 sc[VV / 2];   // 16 KB: -2*c for one half-range
    __shared__ float  sn[VV / 2];   //  4 KB: norm, or FLT_MAX where masked

    const int b   = blockIdx.y;
    const int tid = threadIdx.x;
    const int l   = tid & 31;              // lane within 32-lane row-group
    const int j   = tid >> 5;              // row slot 0..15
    const int v   = blockIdx.x + (j << 7); // strided rows (stride 128): balance

    const float A = active[b];
    int Ai = (int)ceilf(A);
    Ai = Ai < 0 ? 0 : (Ai > VV ? VV : Ai);

    const size_t row = (size_t)b * VV + v;
    const float4* cg = reinterpret_cast<const float4*>(coords + (size_t)b * VV * SS);

    const bool rowActive = ((float)v < A);
    const bool heavy = (__ballot(rowActive) != 0ULL);   // wave-uniform

    const float4 cv = cg[v];
    float qp0 = cv.x*cv.x, qp1 = cv.y*cv.y, qp2 = cv.z*cv.z, qp3 = cv.w*cv.w;
    const float nv  = ((qp0 + qp1) + qp2) + qp3;
    const float nvp = rowActive ? nv : FLT_MAX;   // v-mask folded into nv

    double top[KK];                 // running top-8, sorted asc (cvt-packed)

    int ntiles = (Ai + 31) >> 5;                 // candidate tiles (32 wide)
    if (ntiles < 8) ntiles = 8;                  // >= 8 keys/lane
    const int nb8 = (ntiles + 7) >> 3;           // batches of 8 tiles, 1..8

// stage -2*c and masked norm; LIM entries of half-range P (512-thread stride)
#define STAGE(P, LIM)                                                          \
    for (int i = tid; i < (LIM); i += 512) {                                   \
        const float4 c = cg[i + ((P) << 10)];                                  \
        float p0 = c.x*c.x, p1 = c.y*c.y, p2 = c.z*c.z, p3 = c.w*c.w;          \
        const float nrm = ((p0 + p1) + p2) + p3;                               \
        sn[i] = ((i + ((P) << 10)) < Ai) ? nrm : FLT_MAX;                      \
        float4 c2;                                                             \
        c2.x = -2.0f*c.x; c2.y = -2.0f*c.y;                                    \
        c2.z = -2.0f*c.z; c2.w = -2.0f*c.w;     /* exact scaling */            \
        sc[i] = c2;                                                            \
    }

    // ---- pass 1: candidates w in [0, 1024), batches 0..3 (static) ----
    STAGE(0, VV / 2)
    __syncthreads();
    if (heavy) {
        BATCH_FILL(0, top)                        // peeled: batch 0 IS top
        if (nb8 > 1) BATCH_MERGE(1)
        if (nb8 > 2) BATCH_MERGE(2)
        if (nb8 > 3) BATCH_MERGE(3)
    }

    // ---- pass 2: candidates w in [1024, 2048), batches 4..7 (static) ----
    if (nb8 > 4) {
        const int lim2 = (nb8 << 8) - 1024;       // 256/512/768/1024 entries
        __syncthreads();          // everyone done reading pass-1 LDS
        STAGE(1, lim2)
        __syncthreads();
        if (heavy) {
            BATCH_MERGE(4)
            if (nb8 > 5) BATCH_MERGE(5)
            if (nb8 > 6) BATCH_MERGE(6)
            if (nb8 > 7) BATCH_MERGE(7)
        }
    }
#undef STAGE

    // ---- trivial rows: top-8 of an all-masked row = indices 0..7 ----
    if (!heavy) {
        if (l >= 1 && l < KK)
            out_dist[row * (KK - 1) + (l - 1)] = BF16_SAFE_MAX;
#pragma unroll
        for (int r = 1; r < KK; ++r) {
            const float2 val = reinterpret_cast<const float2*>(
                feats + ((size_t)b * VV + r) * FF)[l];
            reinterpret_cast<float2*>(out_feat + (row * (KK - 1) + (r - 1)) * FF)[l] = val;
        }
        return;
    }

    // ---- 5-level truncated bitonic merge across the 32-lane group ----
#pragma unroll
    for (int step = 1; step < 32; step <<= 1) {
        double t[KK];
#pragma unroll
        for (int i = 0; i < KK; ++i) {
            double pb = shfl_xor_f64(top[KK - 1 - i], step);
            t[i] = fmin(top[i], pb);
        }
        CLEAN8D(t)
#pragma unroll
        for (int i = 0; i < KK; ++i) top[i] = t[i];
    }
    // all 32 lanes hold the row's top-8 ascending; rank 0 = self/dropped

    // ---- epilogue ----
    float dsel = 0.0f;
#pragma unroll
    for (int r = 1; r < KK; ++r) dsel = (l == r) ? (float)top[r] : dsel;
    if (l >= 1 && l < KK) {
        float d = dsel;           // exact f32 distance (cvt rounds back exactly)
        if (!(d <= BF16_SAFE_MAX)) d = BF16_SAFE_MAX;  // finite under bf16
        out_dist[row * (KK - 1) + (l - 1)] = d;
    }

#pragma unroll
    for (int r = 1; r < KK; ++r) {
        const u32 idx = key_idx(top[r]);
        const float2 val = reinterpret_cast<const float2*>(
            feats + ((size_t)b * VV + idx) * FF)[l];
        reinterpret_cast<float2*>(out_feat + (row * (KK - 1) + (r - 1)) * FF)[l] = val;
    }
}

extern "C" void kernel_launch(void* const* d_in, const int* in_sizes, int n_in,
                              void* d_out, int out_size, void* d_ws, size_t ws_size,
                              hipStream_t stream)
{
    const float* coords = (const float*)d_in[0];
    const float* feats  = (const float*)d_in[1];
    const float* act    = (const float*)d_in[2];
    float* out_dist = (float*)d_out;
    float* out_feat = out_dist + (size_t)BB * VV * (KK - 1);

    // 1024 blocks = 256 CU x 4 blocks/CU at 512 threads: single round,
    // full 2048-thread CU occupancy, 16 strided rows per block.
    dim3 grid(VV / 16, BB);
    knn_topk_kernel<<<grid, dim3(512), 0, stream>>>(coords, feats, act,
                                                    out_dist, out_feat);
}